// Round 1
// baseline (5203.289 us; speedup 1.0000x reference)
//
#include <hip/hip_runtime.h>
#include <math.h>

#define NB 256      // events
#define NSV 64
#define NTRK 512
#define NPFC 512
#define KNN 8
#define HD 32

__device__ __forceinline__ float elu_f(float x) {
    return x > 0.f ? x : __expf(x) - 1.f;
}

// ---------------- encoder: out = elu(elu(x@W1+b1)@W2+b2) ----------------
template<int FIN>
__global__ __launch_bounds__(256) void encode_kernel(
    const float* __restrict__ x, const float* __restrict__ W1, const float* __restrict__ b1,
    const float* __restrict__ W2, const float* __restrict__ b2,
    float* __restrict__ out, int n_nodes)
{
    __shared__ float sW1[FIN * 32];
    __shared__ float sW2[32 * 32];
    __shared__ float sb1[32], sb2[32];
    __shared__ float sx[8][FIN];
    __shared__ float sh[8][32];
    int tid = threadIdx.x;
    for (int i = tid; i < FIN * 32; i += 256) sW1[i] = W1[i];
    for (int i = tid; i < 32 * 32; i += 256) sW2[i] = W2[i];
    if (tid < 32) { sb1[tid] = b1[tid]; sb2[tid] = b2[tid]; }
    int node0 = blockIdx.x * 8;
    for (int i = tid; i < 8 * FIN; i += 256) {
        int nn = i / FIN, f = i - nn * FIN;
        int node = node0 + nn;
        sx[nn][f] = (node < n_nodes) ? x[(size_t)node * FIN + f] : 0.f;
    }
    __syncthreads();
    int ln = tid >> 5, c = tid & 31;
    float h = sb1[c];
#pragma unroll
    for (int f = 0; f < FIN; f++) h = fmaf(sx[ln][f], sW1[f * 32 + c], h);
    h = elu_f(h);
    sh[ln][c] = h;
    __syncthreads();
    float o = sb2[c];
#pragma unroll
    for (int k = 0; k < 32; k++) o = fmaf(sh[ln][k], sW2[k * 32 + c], o);
    o = elu_f(o);
    int node = node0 + ln;
    if (node < n_nodes) out[(size_t)node * 32 + c] = o;
}

// ---------------- weight prep: Wd = W[0:32]-W[32:64], W2h = W[32:64] ----------------
__global__ void prep_w_kernel(const float* __restrict__ W, const float* __restrict__ b,
                              float* __restrict__ wd, float* __restrict__ w2h,
                              float* __restrict__ bb)
{
    int i = threadIdx.x + blockIdx.x * blockDim.x;
    if (i < 1024) {
        float lo = W[i], hi = W[1024 + i];
        wd[i] = lo - hi;
        w2h[i] = hi;
    }
    if (i < 32) bb[i] = b[i];
}

// ---------------- edge conv: kNN(K=8) + edge MLP + max-agg ----------------
// src [B,NS,32], dst [B,512,32], out [B,512,32]
// One block = one (event, half of dst nodes). 4 waves; each wave owns one dst
// node at a time: lanes split the NS source rows for distances, iterative
// wave-argmin picks top-8, then edge MLP (2 neighbors/pass * 4 passes).
template<int NS>
__global__ __launch_bounds__(256, 2) void edgeconv_kernel(
    const float* __restrict__ src, const float* __restrict__ dst,
    const float* __restrict__ Wd, const float* __restrict__ W2h,
    const float* __restrict__ bias, float* __restrict__ out)
{
    constexpr int NJ = NS / 64;
    __shared__ float s_src[NS * 32];   // XOR-swizzled: (s,d) at s*32 + (d ^ (s&31))
    int b  = blockIdx.x >> 1;
    int hb = blockIdx.x & 1;
    int tid = threadIdx.x;
    int lane = tid & 63;
    int wave = tid >> 6;

    // stage source rows (swizzled)
    const float4* src4 = (const float4*)(src + (size_t)b * NS * 32);
    for (int i = tid; i < NS * 8; i += 256) {
        int s = i >> 3, q = i & 7;
        float4 v = src4[i];
        int base = s * 32, sw = s & 31;
        s_src[base + ((q * 4 + 0) ^ sw)] = v.x;
        s_src[base + ((q * 4 + 1) ^ sw)] = v.y;
        s_src[base + ((q * 4 + 2) ^ sw)] = v.z;
        s_src[base + ((q * 4 + 3) ^ sw)] = v.w;
    }
    __syncthreads();

    // per-lane norms of this lane's NJ source rows
    float nrm[NJ];
#pragma unroll
    for (int j = 0; j < NJ; j++) {
        int s = lane + 64 * j, sw = s & 31;
        float a = 0.f;
#pragma unroll
        for (int d = 0; d < 32; d++) { float v = s_src[s * 32 + (d ^ sw)]; a = fmaf(v, v, a); }
        nrm[j] = a;
    }

    // per-lane copy of the weight columns for c = lane&31 (registers)
    int c = lane & 31;
    float wdr[32], w2r[32];
#pragma unroll
    for (int d = 0; d < 32; d++) { wdr[d] = Wd[d * 32 + c]; w2r[d] = W2h[d * 32 + c]; }
    float bc = bias[c];
    int hsel = lane >> 5;

    for (int tl = wave; tl < 256; tl += 4) {
        int t = hb * 256 + tl;
        const float4* xi4 = (const float4*)(dst + ((size_t)b * 512 + t) * 32);
        float xi[32];
#pragma unroll
        for (int q = 0; q < 8; q++) {
            float4 v = xi4[q];
            xi[q * 4 + 0] = v.x; xi[q * 4 + 1] = v.y;
            xi[q * 4 + 2] = v.z; xi[q * 4 + 3] = v.w;
        }
        // distances (ranking value: |src|^2 - 2<dst,src>; |dst|^2 constant per dst)
        float dv[NJ];
#pragma unroll
        for (int j = 0; j < NJ; j++) {
            int s = lane + 64 * j, sw = s & 31;
            float acc = 0.f;
#pragma unroll
            for (int d = 0; d < 32; d++) acc = fmaf(xi[d], s_src[s * 32 + (d ^ sw)], acc);
            dv[j] = nrm[j] - 2.f * acc;
        }
        // top-8 smallest, tie-break on lower src index
        int sel[KNN];
#pragma unroll
        for (int k = 0; k < KNN; k++) {
            float bv = dv[0]; int bj = 0;
#pragma unroll
            for (int j = 1; j < NJ; j++) if (dv[j] < bv) { bv = dv[j]; bj = j; }
            int bs = lane + 64 * bj;
#pragma unroll
            for (int off = 32; off >= 1; off >>= 1) {
                float ov = __shfl_down(bv, off);
                int   os = __shfl_down(bs, off);
                if (ov < bv || (ov == bv && os < bs)) { bv = ov; bs = os; }
            }
            bs = __shfl(bs, 0);
            sel[k] = bs;
#pragma unroll
            for (int j = 0; j < NJ; j++) if (bs == lane + 64 * j) dv[j] = 1e30f;
        }
        // edge MLP: m_c = elu(b_c + sum_d xi[d]*Wd[d][c] + sum_d xj[d]*W2h[d][c]); max over 8
        float base = bc;
#pragma unroll
        for (int d = 0; d < 32; d++) base = fmaf(xi[d], wdr[d], base);
        float mx = -1e30f;
#pragma unroll
        for (int p = 0; p < 4; p++) {
            int r = hsel ? sel[2 * p + 1] : sel[2 * p];
            int sw = r & 31;
            float acc = base;
#pragma unroll
            for (int d = 0; d < 32; d++) acc = fmaf(s_src[r * 32 + (d ^ sw)], w2r[d], acc);
            mx = fmaxf(mx, elu_f(acc));
        }
        mx = fmaxf(mx, __shfl_xor(mx, 32));
        if (lane < 32) out[((size_t)b * 512 + t) * 32 + c] = mx;
    }
}

// ---------------- mean pool + out MLP + sigmoid + arange ----------------
__global__ __launch_bounds__(64) void final_kernel(
    const float* __restrict__ f3,
    const float* __restrict__ W1, const float* __restrict__ b1,
    const float* __restrict__ W2, const float* __restrict__ b2,
    float* __restrict__ outp)
{
    int b = blockIdx.x;
    int lane = threadIdx.x;
    int c = lane & 31, hh = lane >> 5;
    const float* base = f3 + (size_t)b * 512 * 32;
    float s = 0.f;
    for (int r = hh; r < 512; r += 2) s += base[r * 32 + c];
    s += __shfl_xor(s, 32);
    float pooled = s * (1.0f / 512.0f);
    __shared__ float sp[32];
    __shared__ float sh1[32];
    if (lane < 32) sp[c] = pooled;
    __syncthreads();
    if (lane < 32) {
        float h = b1[c];
#pragma unroll
        for (int d = 0; d < 32; d++) h = fmaf(sp[d], W1[d * 32 + c], h);
        sh1[c] = elu_f(h);
    }
    __syncthreads();
    if (lane == 0) {
        float o = b2[0];
#pragma unroll
        for (int d = 0; d < 32; d++) o = fmaf(sh1[d], W2[d], o);
        o = 1.f / (1.f + __expf(-o));
        outp[b] = o;                 // output 0: sigmoid [B,1]
        outp[NB + b] = (float)b;     // output 1: arange(B)
    }
}

extern "C" void kernel_launch(void* const* d_in, const int* in_sizes, int n_in,
                              void* d_out, int out_size, void* d_ws, size_t ws_size,
                              hipStream_t stream) {
    const float* x_sv  = (const float*)d_in[0];
    const float* x_trk = (const float*)d_in[1];
    const float* x_pfc = (const float*)d_in[2];
    // d_in[3..5] = batch indices (regular structure, unused)
    const float* sv_W1  = (const float*)d_in[6];
    const float* sv_b1  = (const float*)d_in[7];
    const float* sv_W2  = (const float*)d_in[8];
    const float* sv_b2  = (const float*)d_in[9];
    const float* trk_W1 = (const float*)d_in[10];
    const float* trk_b1 = (const float*)d_in[11];
    const float* trk_W2 = (const float*)d_in[12];
    const float* trk_b2 = (const float*)d_in[13];
    const float* pfc_W1 = (const float*)d_in[14];
    const float* pfc_b1 = (const float*)d_in[15];
    const float* pfc_W2 = (const float*)d_in[16];
    const float* pfc_b2 = (const float*)d_in[17];
    const float* conv_W = (const float*)d_in[18];
    const float* conv_b = (const float*)d_in[19];
    const float* out_W1 = (const float*)d_in[20];
    const float* out_b1 = (const float*)d_in[21];
    const float* out_W2 = (const float*)d_in[22];
    const float* out_b2 = (const float*)d_in[23];

    float* ws = (float*)d_ws;
    const size_t SV_E  = (size_t)NB * NSV * HD;    // 524288
    const size_t TRK_E = (size_t)NB * NTRK * HD;   // 4194304
    float* sv_enc  = ws;
    float* trk_enc = sv_enc + SV_E;
    float* pfc_enc = trk_enc + TRK_E;
    float* f1      = pfc_enc + TRK_E;
    float* f2      = f1 + TRK_E;
    float* wd      = f2 + TRK_E;
    float* w2h     = wd + 1024;
    float* bb      = w2h + 1024;
    float* f3      = trk_enc;  // trk_enc is dead after conv2 -> reuse for feats3

    prep_w_kernel<<<1, 1024, 0, stream>>>(conv_W, conv_b, wd, w2h, bb);

    encode_kernel<14><<<(NB * NSV) / 8, 256, 0, stream>>>(x_sv, sv_W1, sv_b1, sv_W2, sv_b2, sv_enc, NB * NSV);
    encode_kernel<30><<<(NB * NTRK) / 8, 256, 0, stream>>>(x_trk, trk_W1, trk_b1, trk_W2, trk_b2, trk_enc, NB * NTRK);
    encode_kernel<10><<<(NB * NPFC) / 8, 256, 0, stream>>>(x_pfc, pfc_W1, pfc_b1, pfc_W2, pfc_b2, pfc_enc, NB * NPFC);

    edgeconv_kernel<64> <<<NB * 2, 256, 0, stream>>>(sv_enc,  trk_enc, wd, w2h, bb, f1);  // sv -> trk
    edgeconv_kernel<512><<<NB * 2, 256, 0, stream>>>(pfc_enc, trk_enc, wd, w2h, bb, f2);  // pfc -> trk
    edgeconv_kernel<512><<<NB * 2, 256, 0, stream>>>(f1,      f2,      wd, w2h, bb, f3);  // f1 -> f2

    final_kernel<<<NB, 64, 0, stream>>>(f3, out_W1, out_b1, out_W2, out_b2, (float*)d_out);
}